// Round 6
// baseline (226.366 us; speedup 1.0000x reference)
//
#include <hip/hip_runtime.h>

// Problem constants
#define BATCH 8
#define CCH   384      // channels C == INNER
#define NTOK  1024     // H*W
#define HEADS 6
#define DHEAD 64
#define SCALE 0.125f   // 1/sqrt(64)

typedef __bf16 bf16x8 __attribute__((ext_vector_type(8)));
typedef float  f32x4  __attribute__((ext_vector_type(4)));

#define MFMA16(a, b, c) __builtin_amdgcn_mfma_f32_16x16x32_bf16((a), (b), (c), 0, 0, 0)

// fp32 -> bf16 RNE, raw bits
__device__ __forceinline__ short f2b(float x) {
    unsigned u = __float_as_uint(x);
    u += 0x7fffu + ((u >> 16) & 1u);
    return (short)(u >> 16);
}

// async global->LDS, 16B/lane. LDS dst = wave-uniform base + lane*16.
__device__ __forceinline__ void gld_lds16(const short* gp, short* lp) {
    __builtin_amdgcn_global_load_lds(
        (const __attribute__((address_space(1))) void*)gp,
        (__attribute__((address_space(3))) void*)lp, 16, 0, 0);
}

// ---- 64x64 xor-swizzled tile staging (attn K/V) — verified r3/r4 ----
__device__ __forceinline__ void stage_tile(const short* gbase, size_t gstride,
                                           short* lbase, int wv, int lane) {
#pragma unroll
    for (int t = 0; t < 2; ++t) {
        const int row = t * 8 + (lane >> 3);
        const int c   = (lane & 7) ^ (row & 7);
        gld_lds16(gbase + (size_t)(wv * 16 + row) * gstride + c * 8,
                  lbase + (wv * 16 + t * 8) * 64);
    }
}
__device__ __forceinline__ bf16x8 frag_read(const short* lbase, int row, int c) {
    const int pc = c ^ (row & 7);
    return *(const bf16x8*)(lbase + row * 64 + pc * 8);
}

// ---- 128x32 panel staging for gemm128 (rows 64B contiguous, no swizzle) ----
__device__ __forceinline__ void stage_panel32(const short* g, short* l,
                                              int wv, int lane) {
#pragma unroll
    for (int t = 0; t < 2; ++t) {
        const int rg  = wv * 2 + t;                 // 16-row group
        const int row = rg * 16 + (lane >> 2);
        gld_lds16(g + (size_t)row * CCH + (lane & 3) * 8, l + rg * 512);
    }
}

// ---------------------------------------------------------------------------
// gemm128 core: C[128x128] = A[128x384] · B[128x384]^T, both k-contig rows
// stride CCH. Double-buffered BK=32, global_load_lds staging, 192 MFMA/wave.
// ---------------------------------------------------------------------------
__device__ __forceinline__ void gemm128_core(
    const short* __restrict__ Ag, const short* __restrict__ Bg,
    short* Ast, short* Bst, f32x4 acc[4][4])
{
    const int tid = threadIdx.x, lane = tid & 63;
    const int l15 = tid & 15, quad = (tid >> 4) & 3, wv = tid >> 6;
    const int wi = (wv >> 1) * 64, wj = (wv & 1) * 64;

    stage_panel32(Ag, Ast, wv, lane);
    stage_panel32(Bg, Bst, wv, lane);
    __syncthreads();

#pragma unroll 2
    for (int kc = 0; kc < 12; ++kc) {
        const int cur = kc & 1;
        if (kc < 11) {
            stage_panel32(Ag + (kc + 1) * 32, Ast + (cur ^ 1) * 4096, wv, lane);
            stage_panel32(Bg + (kc + 1) * 32, Bst + (cur ^ 1) * 4096, wv, lane);
        }
        bf16x8 a[4], b[4];
#pragma unroll
        for (int s = 0; s < 4; ++s) {
            a[s] = *(const bf16x8*)(Ast + cur * 4096 + (wi + s * 16 + l15) * 32 + quad * 8);
            b[s] = *(const bf16x8*)(Bst + cur * 4096 + (wj + s * 16 + l15) * 32 + quad * 8);
        }
#pragma unroll
        for (int si = 0; si < 4; ++si)
#pragma unroll
            for (int sj = 0; sj < 4; ++sj)
                acc[si][sj] = MFMA16(a[si], b[sj], acc[si][sj]);
        __syncthreads();
    }
}

// Epilogue: repack the 128x128 bf16 C-tile through the (now free) 32 KB of
// Ast/Bst so global stores are b128. Waves 0,1 own rows 0..63 (-> Ast),
// waves 2,3 rows 64..127 (-> Bst). Then 16 lanes cover one row (256 B).
__device__ __forceinline__ void epilogue_bf16(
    f32x4 acc[4][4], short* Ast, short* Bst,
    short* __restrict__ out, size_t obase, int ostride)
{
    const int tid = threadIdx.x;
    const int l15 = tid & 15, quad = (tid >> 4) & 3, wv = tid >> 6;
    const int wj = (wv & 1) * 64;
    short* Cw = (wv >> 1) ? Bst : Ast;   // 64 rows x 128 shorts
#pragma unroll
    for (int si = 0; si < 4; ++si)
#pragma unroll
        for (int sj = 0; sj < 4; ++sj)
#pragma unroll
            for (int rr = 0; rr < 4; ++rr)
                Cw[(si * 16 + quad * 4 + rr) * 128 + wj + sj * 16 + l15] =
                    f2b(acc[si][sj][rr]);
    __syncthreads();
#pragma unroll
    for (int pass = 0; pass < 8; ++pass) {
        const int row = pass * 16 + (tid >> 4);     // 0..127
        const short* Cr = (row < 64) ? Ast : Bst;
        bf16x8 vchunk = *(const bf16x8*)(Cr + (row & 63) * 128 + l15 * 8);
        *(bf16x8*)(out + obase + (size_t)row * ostride + l15 * 8) = vchunk;
    }
}

// ---------------------------------------------------------------------------
// prep: fused transpose+convert (id<1536), weight convert (id<2112),
// amap zero (id>=2112). grid 2120.
// ---------------------------------------------------------------------------
__global__ __launch_bounds__(256) void prep(
    const float* __restrict__ Xq, const float* __restrict__ Xc,
    const float* __restrict__ w0, const float* __restrict__ w1,
    const float* __restrict__ w2, const float* __restrict__ w3,
    short* __restrict__ Xtq, short* __restrict__ Xtc,
    short* __restrict__ o0, short* __restrict__ o1,
    short* __restrict__ o2, short* __restrict__ o3,
    float* __restrict__ amap)
{
    __shared__ float tile[64][65];
    const int id = blockIdx.x, tid = threadIdx.x;
    if (id < 1536) {
        const int zz = id % 16, t = id / 16;
        const int n0 = (t % 16) * 64, c0 = (t / 16) * 64;
        const float* X = (zz < 8) ? Xq : Xc;
        short* Xt      = (zz < 8) ? Xtq : Xtc;
        const int b = zz & 7;
        const int tx = tid & 15, ty = tid >> 4;
#pragma unroll
        for (int rr = 0; rr < 4; ++rr) {
            const int c = rr * 16 + ty;
            float4 v = *(const float4*)&X[((size_t)(b * CCH + c0 + c)) * NTOK + n0 + tx * 4];
            tile[c][tx * 4 + 0] = v.x; tile[c][tx * 4 + 1] = v.y;
            tile[c][tx * 4 + 2] = v.z; tile[c][tx * 4 + 3] = v.w;
        }
        __syncthreads();
        const int n = tid >> 2, cb = (tid & 3) * 16;
        short tmp[16];
#pragma unroll
        for (int cc = 0; cc < 16; ++cc) tmp[cc] = f2b(tile[cb + cc][n]);
        short* dst = &Xt[((size_t)(b * NTOK + n0 + n)) * CCH + c0 + cb];
        *(int4*)dst = *(int4*)&tmp[0];
        *(int4*)(dst + 8) = *(int4*)&tmp[8];
    } else if (id < 2112) {
        const int w = id - 1536;
        const int which = w / 144;
        const int idx = (w % 144) * 256 + tid;
        const float* s = which == 0 ? w0 : which == 1 ? w1 : which == 2 ? w2 : w3;
        short* d       = which == 0 ? o0 : which == 1 ? o1 : which == 2 ? o2 : o3;
        float4 v = ((const float4*)s)[idx];
        short4 o = make_short4(f2b(v.x), f2b(v.y), f2b(v.z), f2b(v.w));
        ((short4*)d)[idx] = o;
    } else {
        const int o = (id - 2112) * 1024 + tid * 4;
        float4 z = {0.f, 0.f, 0.f, 0.f};
        *(float4*)&amap[o] = z;
    }
}

// ---------------------------------------------------------------------------
// Fused QKV projection, 128x128 tiles. 576 blocks: b=id%8 (XCD-local),
// r=id/8: which=r/24 (0:Q,1:K tok-major; 2:V ch-major), tt=r%24.
// ---------------------------------------------------------------------------
__global__ __launch_bounds__(256, 2) void gemm_qkv(
    const short* __restrict__ xtq, const short* __restrict__ xtc,
    const short* __restrict__ wq, const short* __restrict__ wk,
    const short* __restrict__ wvm,
    short* __restrict__ qout, short* __restrict__ kout, short* __restrict__ vout)
{
    __shared__ __align__(16) short Ast[2][4096];
    __shared__ __align__(16) short Bst[2][4096];
    const int id = blockIdx.x;
    const int b = id & 7, r = id >> 3;
    const int which = r / 24, tt = r % 24;

    const short *Ag, *Bg;
    short* out;
    size_t obase;
    int ostride;
    if (which < 2) {
        const int it = tt / 3, jt = tt % 3;
        const short* x = (which == 0) ? xtq : xtc;
        const short* W = (which == 0) ? wq : wk;
        Ag = x + ((size_t)(b * NTOK + it * 128)) * CCH;
        Bg = W + (size_t)(jt * 128) * CCH;
        out = (which == 0) ? qout : kout;
        obase = ((size_t)(b * NTOK + it * 128)) * CCH + jt * 128;
        ostride = CCH;
    } else {
        const int ct = tt % 3, nt = tt / 3;
        Ag = wvm + (size_t)(ct * 128) * CCH;
        Bg = xtc + ((size_t)(b * NTOK + nt * 128)) * CCH;
        out = vout;
        obase = ((size_t)(b * CCH + ct * 128)) * NTOK + nt * 128;
        ostride = NTOK;
    }

    f32x4 z4 = {0.f, 0.f, 0.f, 0.f};
    f32x4 acc[4][4];
#pragma unroll
    for (int si = 0; si < 4; ++si)
#pragma unroll
        for (int sj = 0; sj < 4; ++sj) acc[si][sj] = z4;

    gemm128_core(Ag, Bg, &Ast[0][0], &Bst[0][0], acc);
    epilogue_bf16(acc, &Ast[0][0], &Bst[0][0], out, obase, ostride);
}

// ---------------------------------------------------------------------------
// Output projection, 128x128 tiles, fp32 out + bias. 192 blocks.
// ---------------------------------------------------------------------------
__global__ __launch_bounds__(256, 2) void o_proj(
    const short* __restrict__ wo, const short* __restrict__ omid,
    const float* __restrict__ bias, float* __restrict__ Y)
{
    __shared__ __align__(16) short Ast[2][4096];
    __shared__ __align__(16) short Bst[2][4096];
    const int id = blockIdx.x;
    const int b = id & 7, r = id >> 3;
    const int ct = r % 3, nt = r / 3;

    const short* Ag = wo + (size_t)(ct * 128) * CCH;
    const short* Bg = omid + ((size_t)(b * NTOK + nt * 128)) * CCH;

    f32x4 z4 = {0.f, 0.f, 0.f, 0.f};
    f32x4 acc[4][4];
#pragma unroll
    for (int si = 0; si < 4; ++si)
#pragma unroll
        for (int sj = 0; sj < 4; ++sj) acc[si][sj] = z4;

    gemm128_core(Ag, Bg, &Ast[0][0], &Bst[0][0], acc);

    const int tid = threadIdx.x;
    const int l15 = tid & 15, quad = (tid >> 4) & 3, wv = tid >> 6;
    const int wi = (wv >> 1) * 64, wj = (wv & 1) * 64;
#pragma unroll
    for (int si = 0; si < 4; ++si) {
#pragma unroll
        for (int rr = 0; rr < 4; ++rr) {
            const int ch = ct * 128 + wi + si * 16 + quad * 4 + rr;
            const float bv = bias[ch];
#pragma unroll
            for (int sj = 0; sj < 4; ++sj)
                Y[((size_t)(b * CCH + ch)) * NTOK + nt * 128 + wj + sj * 16 + l15] =
                    acc[si][sj][rr] + bv;
        }
    }
}

// ---------------------------------------------------------------------------
// Fused attention, single QK^T pass. 768 blocks: b=id%8; rr: h, i0.
// Phase 1 (FULLY UNROLLED -> ebuf stays in VGPRs): stage K (db), S=QK^T,
//   e=exp(S*scale) packed bf16 pairs into ebuf (128 VGPRs), den in fp32.
// Phase 2 (FULLY UNROLLED): stage V (db), unpack e, colsum (normalized,
//   fma), Pst <- raw e bf16, PV MFMA; O *= rden at store.
// ---------------------------------------------------------------------------
__global__ __launch_bounds__(256, 2) void attn(
    const short* __restrict__ qt, const short* __restrict__ kt,
    const short* __restrict__ vc, short* __restrict__ omid,
    float* __restrict__ amap)
{
    __shared__ __align__(16) short KV[2][64 * 64];    // 16 KB (K then V)
    __shared__ __align__(16) short Pst[4][16][64];    // 8 KB, chunk-xor swizzled
    __shared__ float colbuf[2][4][64];                // 2 KB

    const int tid = threadIdx.x, lane = tid & 63;
    const int l15 = tid & 15, quad = (tid >> 4) & 3, wv = tid >> 6;
    const int id = blockIdx.x;
    const int b = id & 7, rr_ = id >> 3;
    const int h = rr_ % 6, i0 = (rr_ / 6) * 64;

    const size_t hoff = (size_t)b * NTOK * CCH + h * DHEAD;
    const short* Kg = kt + hoff;                                   // stride CCH
    const short* Vg = vc + ((size_t)(b * CCH + h * DHEAD)) * NTOK; // stride NTOK

    const short* qp = qt + hoff + (size_t)(i0 + wv * 16 + l15) * CCH + quad * 8;
    const bf16x8 qa0 = *(const bf16x8*)qp;
    const bf16x8 qa1 = *(const bf16x8*)(qp + 32);

    int ebuf[16][8];   // 16 jt x (4 ns x 2 pairs) packed bf16 — MUST stay VGPR

    // ---------------- Phase 1: QK^T + exp + den ----------------
    stage_tile(Kg, CCH, KV[0], wv, lane);
    __syncthreads();

    float den[4] = {0.f, 0.f, 0.f, 0.f};
#pragma unroll
    for (int jt = 0; jt < 16; ++jt) {
        const int cur = jt & 1;
        if (jt < 15)
            stage_tile(Kg + (size_t)(jt + 1) * 64 * CCH, CCH, KV[cur ^ 1], wv, lane);
        f32x4 z4 = {0.f, 0.f, 0.f, 0.f};
        f32x4 s[4] = {z4, z4, z4, z4};
#pragma unroll
        for (int ns = 0; ns < 4; ++ns) {
            const int row = ns * 16 + l15;
            bf16x8 k0 = frag_read(KV[cur], row, quad);
            bf16x8 k1 = frag_read(KV[cur], row, quad + 4);
            s[ns] = MFMA16(qa0, k0, s[ns]);
            s[ns] = MFMA16(qa1, k1, s[ns]);
        }
#pragma unroll
        for (int ns = 0; ns < 4; ++ns) {
#pragma unroll
            for (int p = 0; p < 2; ++p) {
                const float e0 = __expf(s[ns][2 * p]     * SCALE);
                const float e1 = __expf(s[ns][2 * p + 1] * SCALE);
                den[2 * p]     += e0;
                den[2 * p + 1] += e1;
                ebuf[jt][ns * 2 + p] =
                    (int)((unsigned short)f2b(e0)) |
                    ((int)((unsigned short)f2b(e1)) << 16);
            }
        }
        __syncthreads();
    }
#pragma unroll
    for (int r = 0; r < 4; ++r) {
        den[r] += __shfl_xor(den[r], 1);
        den[r] += __shfl_xor(den[r], 2);
        den[r] += __shfl_xor(den[r], 4);
        den[r] += __shfl_xor(den[r], 8);
    }
    float rden[4];
#pragma unroll
    for (int r = 0; r < 4; ++r) rden[r] = 1.0f / den[r];

    // ---------------- Phase 2: colsum + PV ----------------
    stage_tile(Vg, NTOK, KV[0], wv, lane);
    __syncthreads();

    f32x4 z4o = {0.f, 0.f, 0.f, 0.f};
    f32x4 oacc[4] = {z4o, z4o, z4o, z4o};
#pragma unroll
    for (int jt = 0; jt < 16; ++jt) {
        const int cur = jt & 1;
        if (jt < 15)
            stage_tile(Vg + (size_t)(jt + 1) * 64, NTOK, KV[cur ^ 1], wv, lane);

#pragma unroll
        for (int ns = 0; ns < 4; ++ns) {
            const int c = ns * 2 + (l15 >> 3);
            float cs = 0.f;
#pragma unroll
            for (int p = 0; p < 2; ++p) {
                const int w = ebuf[jt][ns * 2 + p];
                const float v0 = __uint_as_float(((unsigned)w) << 16);
                const float v1 = __uint_as_float(((unsigned)w) & 0xffff0000u);
                cs = fmaf(v0, rden[2 * p], cs);
                cs = fmaf(v1, rden[2 * p + 1], cs);
                const int r0 = quad * 4 + 2 * p;
                const int r1 = r0 + 1;
                Pst[wv][r0][((c ^ (r0 & 7)) << 3) | (l15 & 7)] = (short)(w & 0xffff);
                Pst[wv][r1][((c ^ (r1 & 7)) << 3) | (l15 & 7)] = (short)(((unsigned)w) >> 16);
            }
            cs += __shfl_xor(cs, 16);
            cs += __shfl_xor(cs, 32);
            if (quad == 0) colbuf[cur][wv][ns * 16 + l15] = cs;
        }
        asm volatile("" ::: "memory");
        const int pc0 = quad ^ (l15 & 7);
        const int pc1 = (quad + 4) ^ (l15 & 7);
        bf16x8 pa0 = *(const bf16x8*)&Pst[wv][l15][pc0 * 8];
        bf16x8 pa1 = *(const bf16x8*)&Pst[wv][l15][pc1 * 8];
        asm volatile("" ::: "memory");

#pragma unroll
        for (int ds = 0; ds < 4; ++ds) {
            const int row = ds * 16 + l15;
            bf16x8 v0 = frag_read(KV[cur], row, quad);
            bf16x8 v1 = frag_read(KV[cur], row, quad + 4);
            oacc[ds] = MFMA16(pa0, v0, oacc[ds]);
            oacc[ds] = MFMA16(pa1, v1, oacc[ds]);
        }
        __syncthreads();
        if (tid < 64) {
            const float t = colbuf[cur][0][tid] + colbuf[cur][1][tid]
                          + colbuf[cur][2][tid] + colbuf[cur][3][tid];
            atomicAdd(amap + (size_t)b * NTOK + jt * 64 + tid,
                      t * (1.0f / (HEADS * NTOK)));
        }
    }

    // store O (normalize by rden), token-major bf16
#pragma unroll
    for (int ds = 0; ds < 4; ++ds)
#pragma unroll
        for (int r = 0; r < 4; ++r) {
            const int i = i0 + wv * 16 + quad * 4 + r;
            omid[((size_t)(b * NTOK + i)) * CCH + h * DHEAD + ds * 16 + l15] =
                f2b(oacc[ds][r] * rden[r]);
        }
}

// ---------------------------------------------------------------------------
extern "C" void kernel_launch(void* const* d_in, const int* in_sizes, int n_in,
                              void* d_out, int out_size, void* d_ws, size_t ws_size,
                              hipStream_t stream)
{
    const float* query   = (const float*)d_in[0];
    const float* context = (const float*)d_in[1];
    const float* Wq      = (const float*)d_in[2];
    const float* Wk      = (const float*)d_in[3];
    const float* Wv      = (const float*)d_in[4];
    const float* Wo      = (const float*)d_in[5];
    const float* bo      = (const float*)d_in[6];

    float* out = (float*)d_out;                          // [8,384,1024] fp32
    const size_t out_elems = (size_t)BATCH * CCH * NTOK;
    float* attn_map = out + out_elems;                   // [8,1024] fp32

    short* ws = (short*)d_ws;
    const size_t XT = (size_t)BATCH * NTOK * CCH;
    const size_t WSZ = (size_t)CCH * CCH;
    short* xtq  = ws;
    short* xtc  = xtq + XT;
    short* wqb  = xtc + XT;
    short* wkb  = wqb + WSZ;
    short* wvb  = wkb + WSZ;
    short* wob  = wvb + WSZ;
    short* qtb  = wob + WSZ;
    short* ktb  = qtb + XT;
    short* vcb  = ktb + XT;
    short* omid = vcb + XT;

    const dim3 blk(256);

    prep<<<dim3(2120), blk, 0, stream>>>(query, context, Wq, Wk, Wv, Wo,
                                         xtq, xtc, wqb, wkb, wvb, wob, attn_map);

    gemm_qkv<<<dim3(576), blk, 0, stream>>>(xtq, xtc, wqb, wkb, wvb,
                                            qtb, ktb, vcb);

    attn<<<dim3(768), blk, 0, stream>>>(qtb, ktb, vcb, omid, attn_map);

    o_proj<<<dim3(192), blk, 0, stream>>>(wob, omid, bo, out);
}

// Round 7
// 203.409 us; speedup vs baseline: 1.1129x; 1.1129x over previous
//
#include <hip/hip_runtime.h>

// Problem constants
#define BATCH 8
#define CCH   384      // channels C == INNER
#define NTOK  1024     // H*W
#define HEADS 6
#define DHEAD 64
// softmax scale 1/8 folded into Q at projection time together with log2(e):
// qout = Q * 0.125 * 1.4426950408889634, attn uses exp2f(s).
#define QSCALE 0.18033688011112042f

typedef __bf16 bf16x8 __attribute__((ext_vector_type(8)));
typedef float  f32x4  __attribute__((ext_vector_type(4)));
typedef float  f32x2  __attribute__((ext_vector_type(2)));

#define MFMA16(a, b, c) __builtin_amdgcn_mfma_f32_16x16x32_bf16((a), (b), (c), 0, 0, 0)

// fp32 -> bf16 RNE, raw bits
__device__ __forceinline__ short f2b(float x) {
    unsigned u = __float_as_uint(x);
    u += 0x7fffu + ((u >> 16) & 1u);
    return (short)(u >> 16);
}

// async global->LDS, 16B/lane. LDS dst = wave-uniform base + lane*16.
__device__ __forceinline__ void gld_lds16(const short* gp, short* lp) {
    __builtin_amdgcn_global_load_lds(
        (const __attribute__((address_space(1))) void*)gp,
        (__attribute__((address_space(3))) void*)lp, 16, 0, 0);
}

// ---- 64x64 xor-swizzled tile staging — verified r3/r4 ----
__device__ __forceinline__ void stage_tile(const short* gbase, size_t gstride,
                                           short* lbase, int wv, int lane) {
#pragma unroll
    for (int t = 0; t < 2; ++t) {
        const int row = t * 8 + (lane >> 3);
        const int c   = (lane & 7) ^ (row & 7);
        gld_lds16(gbase + (size_t)(wv * 16 + row) * gstride + c * 8,
                  lbase + (wv * 16 + t * 8) * 64);
    }
}
__device__ __forceinline__ bf16x8 frag_read(const short* lbase, int row, int c) {
    const int pc = c ^ (row & 7);
    return *(const bf16x8*)(lbase + row * 64 + pc * 8);
}

// ---------------------------------------------------------------------------
// gemm128 core: C[128x128] = A[128x384] · B[128x384]^T, both k-contig rows,
// stride CCH. BK=64 via two xor-swizzled 64x64 stage_tiles per operand
// (conflict-free frag reads), double-buffered, 6 K-iters.
// Ast/Bst: each [2][8192] shorts (32 KB).
// ---------------------------------------------------------------------------
__device__ __forceinline__ void gemm128_core(
    const short* __restrict__ Ag, const short* __restrict__ Bg,
    short* Ast, short* Bst, f32x4 acc[4][4])
{
    const int tid = threadIdx.x, lane = tid & 63;
    const int l15 = tid & 15, quad = (tid >> 4) & 3, wv = tid >> 6;

    stage_tile(Ag, CCH, Ast, wv, lane);
    stage_tile(Ag + 64 * CCH, CCH, Ast + 4096, wv, lane);
    stage_tile(Bg, CCH, Bst, wv, lane);
    stage_tile(Bg + 64 * CCH, CCH, Bst + 4096, wv, lane);
    __syncthreads();

#pragma unroll
    for (int kc = 0; kc < 6; ++kc) {
        const int cur = kc & 1;
        if (kc < 5) {
            short* An = Ast + (cur ^ 1) * 8192;
            short* Bn = Bst + (cur ^ 1) * 8192;
            stage_tile(Ag + (kc + 1) * 64, CCH, An, wv, lane);
            stage_tile(Ag + (kc + 1) * 64 + 64 * CCH, CCH, An + 4096, wv, lane);
            stage_tile(Bg + (kc + 1) * 64, CCH, Bn, wv, lane);
            stage_tile(Bg + (kc + 1) * 64 + 64 * CCH, CCH, Bn + 4096, wv, lane);
        }
        const short* Atile = Ast + cur * 8192 + (wv >> 1) * 4096;  // wi tile
        const short* Btile = Bst + cur * 8192 + (wv & 1) * 4096;   // wj tile
#pragma unroll
        for (int h = 0; h < 2; ++h) {
            bf16x8 a[4], b[4];
#pragma unroll
            for (int s = 0; s < 4; ++s) {
                a[s] = frag_read(Atile, s * 16 + l15, h * 4 + quad);
                b[s] = frag_read(Btile, s * 16 + l15, h * 4 + quad);
            }
#pragma unroll
            for (int si = 0; si < 4; ++si)
#pragma unroll
                for (int sj = 0; sj < 4; ++sj)
                    acc[si][sj] = MFMA16(a[si], b[sj], acc[si][sj]);
        }
        __syncthreads();
    }
}

// Epilogue: repack the 128x128 bf16 C-tile through cbuf (=Ast, 32 KB, free
// after the K-loop) so global stores are b128.
__device__ __forceinline__ void epilogue_bf16(
    f32x4 acc[4][4], short* cbuf,
    short* __restrict__ out, size_t obase, int ostride)
{
    const int tid = threadIdx.x;
    const int l15 = tid & 15, quad = (tid >> 4) & 3, wv = tid >> 6;
    const int wi = (wv >> 1) * 64, wj = (wv & 1) * 64;
    __syncthreads();   // everyone past the K-loop before reusing Ast
#pragma unroll
    for (int si = 0; si < 4; ++si)
#pragma unroll
        for (int sj = 0; sj < 4; ++sj)
#pragma unroll
            for (int rr = 0; rr < 4; ++rr)
                cbuf[(wi + si * 16 + quad * 4 + rr) * 128 + wj + sj * 16 + l15] =
                    f2b(acc[si][sj][rr]);
    __syncthreads();
#pragma unroll
    for (int pass = 0; pass < 8; ++pass) {
        const int row = pass * 16 + (tid >> 4);     // 0..127
        bf16x8 vchunk = *(const bf16x8*)(cbuf + row * 128 + l15 * 8);
        *(bf16x8*)(out + obase + (size_t)row * ostride + l15 * 8) = vchunk;
    }
}

// ---------------------------------------------------------------------------
// prep: fused transpose+convert (id<1536), weight convert (id<2112),
// amap zero (id>=2112). grid 2120.
// ---------------------------------------------------------------------------
__global__ __launch_bounds__(256) void prep(
    const float* __restrict__ Xq, const float* __restrict__ Xc,
    const float* __restrict__ w0, const float* __restrict__ w1,
    const float* __restrict__ w2, const float* __restrict__ w3,
    short* __restrict__ Xtq, short* __restrict__ Xtc,
    short* __restrict__ o0, short* __restrict__ o1,
    short* __restrict__ o2, short* __restrict__ o3,
    float* __restrict__ amap)
{
    __shared__ float tile[64][65];
    const int id = blockIdx.x, tid = threadIdx.x;
    if (id < 1536) {
        const int zz = id % 16, t = id / 16;
        const int n0 = (t % 16) * 64, c0 = (t / 16) * 64;
        const float* X = (zz < 8) ? Xq : Xc;
        short* Xt      = (zz < 8) ? Xtq : Xtc;
        const int b = zz & 7;
        const int tx = tid & 15, ty = tid >> 4;
#pragma unroll
        for (int rr = 0; rr < 4; ++rr) {
            const int c = rr * 16 + ty;
            float4 v = *(const float4*)&X[((size_t)(b * CCH + c0 + c)) * NTOK + n0 + tx * 4];
            tile[c][tx * 4 + 0] = v.x; tile[c][tx * 4 + 1] = v.y;
            tile[c][tx * 4 + 2] = v.z; tile[c][tx * 4 + 3] = v.w;
        }
        __syncthreads();
        const int n = tid >> 2, cb = (tid & 3) * 16;
        short tmp[16];
#pragma unroll
        for (int cc = 0; cc < 16; ++cc) tmp[cc] = f2b(tile[cb + cc][n]);
        short* dst = &Xt[((size_t)(b * NTOK + n0 + n)) * CCH + c0 + cb];
        *(int4*)dst = *(int4*)&tmp[0];
        *(int4*)(dst + 8) = *(int4*)&tmp[8];
    } else if (id < 2112) {
        const int w = id - 1536;
        const int which = w / 144;
        const int idx = (w % 144) * 256 + tid;
        const float* s = which == 0 ? w0 : which == 1 ? w1 : which == 2 ? w2 : w3;
        short* d       = which == 0 ? o0 : which == 1 ? o1 : which == 2 ? o2 : o3;
        float4 v = ((const float4*)s)[idx];
        short4 o = make_short4(f2b(v.x), f2b(v.y), f2b(v.z), f2b(v.w));
        ((short4*)d)[idx] = o;
    } else {
        const int o = (id - 2112) * 1024 + tid * 4;
        float4 z = {0.f, 0.f, 0.f, 0.f};
        *(float4*)&amap[o] = z;
    }
}

// ---------------------------------------------------------------------------
// Fused QKV projection, 128x128 tiles. 576 blocks: b=id%8 (XCD-local),
// r=id/8: which=r/24 (0:Q,1:K tok-major; 2:V ch-major), tt=r%24.
// Q output pre-scaled by QSCALE (softmax scale * log2e folded in).
// ---------------------------------------------------------------------------
__global__ __launch_bounds__(256, 2) void gemm_qkv(
    const short* __restrict__ xtq, const short* __restrict__ xtc,
    const short* __restrict__ wq, const short* __restrict__ wk,
    const short* __restrict__ wvm,
    short* __restrict__ qout, short* __restrict__ kout, short* __restrict__ vout)
{
    __shared__ __align__(16) short Ast[2][8192];
    __shared__ __align__(16) short Bst[2][8192];
    const int id = blockIdx.x;
    const int b = id & 7, r = id >> 3;
    const int which = r / 24, tt = r % 24;

    const short *Ag, *Bg;
    short* out;
    size_t obase;
    int ostride;
    if (which < 2) {
        const int it = tt / 3, jt = tt % 3;
        const short* x = (which == 0) ? xtq : xtc;
        const short* W = (which == 0) ? wq : wk;
        Ag = x + ((size_t)(b * NTOK + it * 128)) * CCH;
        Bg = W + (size_t)(jt * 128) * CCH;
        out = (which == 0) ? qout : kout;
        obase = ((size_t)(b * NTOK + it * 128)) * CCH + jt * 128;
        ostride = CCH;
    } else {
        const int ct = tt % 3, nt = tt / 3;
        Ag = wvm + (size_t)(ct * 128) * CCH;
        Bg = xtc + ((size_t)(b * NTOK + nt * 128)) * CCH;
        out = vout;
        obase = ((size_t)(b * CCH + ct * 128)) * NTOK + nt * 128;
        ostride = NTOK;
    }

    f32x4 z4 = {0.f, 0.f, 0.f, 0.f};
    f32x4 acc[4][4];
#pragma unroll
    for (int si = 0; si < 4; ++si)
#pragma unroll
        for (int sj = 0; sj < 4; ++sj) acc[si][sj] = z4;

    gemm128_core(Ag, Bg, &Ast[0][0], &Bst[0][0], acc);

    if (which == 0) {
#pragma unroll
        for (int si = 0; si < 4; ++si)
#pragma unroll
            for (int sj = 0; sj < 4; ++sj)
#pragma unroll
                for (int rr = 0; rr < 4; ++rr)
                    acc[si][sj][rr] *= QSCALE;
    }
    epilogue_bf16(acc, &Ast[0][0], out, obase, ostride);
}

// ---------------------------------------------------------------------------
// Output projection, 128x128 tiles, fp32 out + bias. 192 blocks.
// ---------------------------------------------------------------------------
__global__ __launch_bounds__(256, 2) void o_proj(
    const short* __restrict__ wo, const short* __restrict__ omid,
    const float* __restrict__ bias, float* __restrict__ Y)
{
    __shared__ __align__(16) short Ast[2][8192];
    __shared__ __align__(16) short Bst[2][8192];
    const int id = blockIdx.x;
    const int b = id & 7, r = id >> 3;
    const int ct = r % 3, nt = r / 3;

    const short* Ag = wo + (size_t)(ct * 128) * CCH;
    const short* Bg = omid + ((size_t)(b * NTOK + nt * 128)) * CCH;

    f32x4 z4 = {0.f, 0.f, 0.f, 0.f};
    f32x4 acc[4][4];
#pragma unroll
    for (int si = 0; si < 4; ++si)
#pragma unroll
        for (int sj = 0; sj < 4; ++sj) acc[si][sj] = z4;

    gemm128_core(Ag, Bg, &Ast[0][0], &Bst[0][0], acc);

    const int tid = threadIdx.x;
    const int l15 = tid & 15, quad = (tid >> 4) & 3, wv = tid >> 6;
    const int wi = (wv >> 1) * 64, wj = (wv & 1) * 64;
#pragma unroll
    for (int si = 0; si < 4; ++si) {
#pragma unroll
        for (int rr = 0; rr < 4; ++rr) {
            const int ch = ct * 128 + wi + si * 16 + quad * 4 + rr;
            const float bv = bias[ch];
#pragma unroll
            for (int sj = 0; sj < 4; ++sj)
                Y[((size_t)(b * CCH + ch)) * NTOK + nt * 128 + wj + sj * 16 + l15] =
                    acc[si][sj][rr] + bv;
        }
    }
}

// ---------------------------------------------------------------------------
// Fused attention, SINGLE pass. 768 blocks: b=id%8; rr: h, i0.
// Per jt: S=QK^T (Q pre-scaled), e=exp2(s); den += e (fp32); e packed to
// fp8 (e4m3) into ebuf (64 VGPRs) for the amap tail; bf16(e) -> Pst
// (r4-verified swizzle) -> PV MFMA into unnormalized oacc.
// Tail: den shfl-reduce -> rden; O stored * rden; colsums from fp8 ebuf,
// wave shfl + LDS cross-wave combine + 1 atomic per element.
// ---------------------------------------------------------------------------
__global__ __launch_bounds__(256, 2) void attn(
    const short* __restrict__ qt, const short* __restrict__ kt,
    const short* __restrict__ vc, short* __restrict__ omid,
    float* __restrict__ amap)
{
    __shared__ __align__(16) short Kst[2][64 * 64];   // 16 KB
    __shared__ __align__(16) short Vst[2][64 * 64];   // 16 KB
    __shared__ __align__(16) short Pst[4][16][64];    // 8 KB, chunk-xor swizzled
    __shared__ float colbuf[4][1024];                 // 16 KB

    const int tid = threadIdx.x, lane = tid & 63;
    const int l15 = tid & 15, quad = (tid >> 4) & 3, wv = tid >> 6;
    const int id = blockIdx.x;
    const int b = id & 7, rr_ = id >> 3;
    const int h = rr_ % 6, i0 = (rr_ / 6) * 64;

    const size_t hoff = (size_t)b * NTOK * CCH + h * DHEAD;
    const short* Kg = kt + hoff;                                   // stride CCH
    const short* Vg = vc + ((size_t)(b * CCH + h * DHEAD)) * NTOK; // stride NTOK

    const short* qp = qt + hoff + (size_t)(i0 + wv * 16 + l15) * CCH + quad * 8;
    const bf16x8 qa0 = *(const bf16x8*)qp;
    const bf16x8 qa1 = *(const bf16x8*)(qp + 32);

    int ebuf[16][4];   // 16 jt x 4 ns, each int = 4 fp8 (rows r=0..3)

    stage_tile(Kg, CCH, Kst[0], wv, lane);
    stage_tile(Vg, NTOK, Vst[0], wv, lane);
    __syncthreads();

    float den[4] = {0.f, 0.f, 0.f, 0.f};
    f32x4 z4o = {0.f, 0.f, 0.f, 0.f};
    f32x4 oacc[4] = {z4o, z4o, z4o, z4o};

#pragma unroll
    for (int jt = 0; jt < 16; ++jt) {
        const int cur = jt & 1;
        if (jt < 15) {
            stage_tile(Kg + (size_t)(jt + 1) * 64 * CCH, CCH, Kst[cur ^ 1], wv, lane);
            stage_tile(Vg + (size_t)(jt + 1) * 64, NTOK, Vst[cur ^ 1], wv, lane);
        }
        f32x4 s[4] = {z4o, z4o, z4o, z4o};
#pragma unroll
        for (int ns = 0; ns < 4; ++ns) {
            const int row = ns * 16 + l15;
            bf16x8 k0 = frag_read(Kst[cur], row, quad);
            bf16x8 k1 = frag_read(Kst[cur], row, quad + 4);
            s[ns] = MFMA16(qa0, k0, s[ns]);
            s[ns] = MFMA16(qa1, k1, s[ns]);
        }
#pragma unroll
        for (int ns = 0; ns < 4; ++ns) {
            const float e0 = exp2f(s[ns][0]);
            const float e1 = exp2f(s[ns][1]);
            const float e2 = exp2f(s[ns][2]);
            const float e3 = exp2f(s[ns][3]);
            den[0] += e0; den[1] += e1; den[2] += e2; den[3] += e3;
            int w = __builtin_amdgcn_cvt_pk_fp8_f32(e0, e1, 0, false);
            w = __builtin_amdgcn_cvt_pk_fp8_f32(e2, e3, w, true);
            ebuf[jt][ns] = w;
            const int c = ns * 2 + (l15 >> 3);
            const int r0 = quad * 4, r1 = r0 + 1, r2 = r0 + 2, r3 = r0 + 3;
            Pst[wv][r0][((c ^ (r0 & 7)) << 3) | (l15 & 7)] = f2b(e0);
            Pst[wv][r1][((c ^ (r1 & 7)) << 3) | (l15 & 7)] = f2b(e1);
            Pst[wv][r2][((c ^ (r2 & 7)) << 3) | (l15 & 7)] = f2b(e2);
            Pst[wv][r3][((c ^ (r3 & 7)) << 3) | (l15 & 7)] = f2b(e3);
        }
        asm volatile("" ::: "memory");
        const int pc0 = quad ^ (l15 & 7);
        const int pc1 = (quad + 4) ^ (l15 & 7);
        bf16x8 pa0 = *(const bf16x8*)&Pst[wv][l15][pc0 * 8];
        bf16x8 pa1 = *(const bf16x8*)&Pst[wv][l15][pc1 * 8];
        asm volatile("" ::: "memory");

#pragma unroll
        for (int ds = 0; ds < 4; ++ds) {
            const int row = ds * 16 + l15;
            bf16x8 v0 = frag_read(Vst[cur], row, quad);
            bf16x8 v1 = frag_read(Vst[cur], row, quad + 4);
            oacc[ds] = MFMA16(pa0, v0, oacc[ds]);
            oacc[ds] = MFMA16(pa1, v1, oacc[ds]);
        }
        __syncthreads();
    }

    // row-sum reduce across the 16 j-lanes
#pragma unroll
    for (int r = 0; r < 4; ++r) {
        den[r] += __shfl_xor(den[r], 1);
        den[r] += __shfl_xor(den[r], 2);
        den[r] += __shfl_xor(den[r], 4);
        den[r] += __shfl_xor(den[r], 8);
    }
    float rden[4];
#pragma unroll
    for (int r = 0; r < 4; ++r) rden[r] = 1.0f / den[r];

    // store O (normalize by rden), token-major bf16
#pragma unroll
    for (int ds = 0; ds < 4; ++ds)
#pragma unroll
        for (int r = 0; r < 4; ++r) {
            const int i = i0 + wv * 16 + quad * 4 + r;
            omid[((size_t)(b * NTOK + i)) * CCH + h * DHEAD + ds * 16 + l15] =
                f2b(oacc[ds][r] * rden[r]);
        }

    // ---- amap tail: colsums from fp8 ebuf ----
#pragma unroll
    for (int jt = 0; jt < 16; ++jt)
#pragma unroll
        for (int ns = 0; ns < 4; ++ns) {
            const f32x2 lo = __builtin_amdgcn_cvt_pk_f32_fp8(ebuf[jt][ns], false);
            const f32x2 hi = __builtin_amdgcn_cvt_pk_f32_fp8(ebuf[jt][ns], true);
            float cs = lo[0] * rden[0] + lo[1] * rden[1]
                     + hi[0] * rden[2] + hi[1] * rden[3];
            cs += __shfl_xor(cs, 16);
            cs += __shfl_xor(cs, 32);
            if (quad == 0) colbuf[wv][jt * 64 + ns * 16 + l15] = cs;
        }
    __syncthreads();
    for (int idx = tid; idx < 1024; idx += 256) {
        const float t = colbuf[0][idx] + colbuf[1][idx]
                      + colbuf[2][idx] + colbuf[3][idx];
        atomicAdd(amap + (size_t)b * NTOK + idx, t * (1.0f / (HEADS * NTOK)));
    }
}

// ---------------------------------------------------------------------------
extern "C" void kernel_launch(void* const* d_in, const int* in_sizes, int n_in,
                              void* d_out, int out_size, void* d_ws, size_t ws_size,
                              hipStream_t stream)
{
    const float* query   = (const float*)d_in[0];
    const float* context = (const float*)d_in[1];
    const float* Wq      = (const float*)d_in[2];
    const float* Wk      = (const float*)d_in[3];
    const float* Wv      = (const float*)d_in[4];
    const float* Wo      = (const float*)d_in[5];
    const float* bo      = (const float*)d_in[6];

    float* out = (float*)d_out;                          // [8,384,1024] fp32
    const size_t out_elems = (size_t)BATCH * CCH * NTOK;
    float* attn_map = out + out_elems;                   // [8,1024] fp32

    short* ws = (short*)d_ws;
    const size_t XT = (size_t)BATCH * NTOK * CCH;
    const size_t WSZ = (size_t)CCH * CCH;
    short* xtq  = ws;
    short* xtc  = xtq + XT;
    short* wqb  = xtc + XT;
    short* wkb  = wqb + WSZ;
    short* wvb  = wkb + WSZ;
    short* wob  = wvb + WSZ;
    short* qtb  = wob + WSZ;
    short* ktb  = qtb + XT;
    short* vcb  = ktb + XT;
    short* omid = vcb + XT;

    const dim3 blk(256);

    prep<<<dim3(2120), blk, 0, stream>>>(query, context, Wq, Wk, Wv, Wo,
                                         xtq, xtc, wqb, wkb, wvb, wob, attn_map);

    gemm_qkv<<<dim3(576), blk, 0, stream>>>(xtq, xtc, wqb, wkb, wvb,
                                            qtb, ktb, vcb);

    attn<<<dim3(768), blk, 0, stream>>>(qtb, ktb, vcb, omid, attn_map);

    o_proj<<<dim3(192), blk, 0, stream>>>(wob, omid, bo, out);
}

// Round 8
// 167.307 us; speedup vs baseline: 1.3530x; 1.2158x over previous
//
#include <hip/hip_runtime.h>

// Problem constants
#define BATCH 8
#define CCH   384      // channels C == INNER
#define NTOK  1024     // H*W
#define HEADS 6
#define DHEAD 64
// softmax scale 1/8 and log2(e) folded into Q at projection time:
// qout = Q * 0.125 * 1.4426950408889634, attn uses exp2f(s) = bare v_exp.
#define QSCALE 0.18033688011112042f

typedef __bf16 bf16x8 __attribute__((ext_vector_type(8)));
typedef float  f32x4  __attribute__((ext_vector_type(4)));

#define MFMA16(a, b, c) __builtin_amdgcn_mfma_f32_16x16x32_bf16((a), (b), (c), 0, 0, 0)

// fp32 -> bf16 RNE, raw bits
__device__ __forceinline__ short f2b(float x) {
    unsigned u = __float_as_uint(x);
    u += 0x7fffu + ((u >> 16) & 1u);
    return (short)(u >> 16);
}

// async global->LDS, 16B/lane. LDS dst = wave-uniform base + lane*16.
__device__ __forceinline__ void gld_lds16(const short* gp, short* lp) {
    __builtin_amdgcn_global_load_lds(
        (const __attribute__((address_space(1))) void*)gp,
        (__attribute__((address_space(3))) void*)lp, 16, 0, 0);
}

// ---- 64x64 xor-swizzled tile staging — verified r3/r4 ----
__device__ __forceinline__ void stage_tile(const short* gbase, size_t gstride,
                                           short* lbase, int wv, int lane) {
#pragma unroll
    for (int t = 0; t < 2; ++t) {
        const int row = t * 8 + (lane >> 3);
        const int c   = (lane & 7) ^ (row & 7);
        gld_lds16(gbase + (size_t)(wv * 16 + row) * gstride + c * 8,
                  lbase + (wv * 16 + t * 8) * 64);
    }
}
__device__ __forceinline__ bf16x8 frag_read(const short* lbase, int row, int c) {
    const int pc = c ^ (row & 7);
    return *(const bf16x8*)(lbase + row * 64 + pc * 8);
}

// ---------------------------------------------------------------------------
// gemm128 core: C[128x128] = A[128x384] · B[128x384]^T, both k-contig rows,
// stride CCH. BK=64 via two xor-swizzled 64x64 stage_tiles per operand
// (conflict-free frag reads), double-buffered, 6 K-iters.
// ---------------------------------------------------------------------------
__device__ __forceinline__ void gemm128_core(
    const short* __restrict__ Ag, const short* __restrict__ Bg,
    short* Ast, short* Bst, f32x4 acc[4][4])
{
    const int tid = threadIdx.x, lane = tid & 63;
    const int l15 = tid & 15, quad = (tid >> 4) & 3, wv = tid >> 6;

    stage_tile(Ag, CCH, Ast, wv, lane);
    stage_tile(Ag + 64 * CCH, CCH, Ast + 4096, wv, lane);
    stage_tile(Bg, CCH, Bst, wv, lane);
    stage_tile(Bg + 64 * CCH, CCH, Bst + 4096, wv, lane);
    __syncthreads();

#pragma unroll
    for (int kc = 0; kc < 6; ++kc) {
        const int cur = kc & 1;
        if (kc < 5) {
            short* An = Ast + (cur ^ 1) * 8192;
            short* Bn = Bst + (cur ^ 1) * 8192;
            stage_tile(Ag + (kc + 1) * 64, CCH, An, wv, lane);
            stage_tile(Ag + (kc + 1) * 64 + 64 * CCH, CCH, An + 4096, wv, lane);
            stage_tile(Bg + (kc + 1) * 64, CCH, Bn, wv, lane);
            stage_tile(Bg + (kc + 1) * 64 + 64 * CCH, CCH, Bn + 4096, wv, lane);
        }
        const short* Atile = Ast + cur * 8192 + (wv >> 1) * 4096;  // wi tile
        const short* Btile = Bst + cur * 8192 + (wv & 1) * 4096;   // wj tile
#pragma unroll
        for (int h = 0; h < 2; ++h) {
            bf16x8 a[4], b[4];
#pragma unroll
            for (int s = 0; s < 4; ++s) {
                a[s] = frag_read(Atile, s * 16 + l15, h * 4 + quad);
                b[s] = frag_read(Btile, s * 16 + l15, h * 4 + quad);
            }
#pragma unroll
            for (int si = 0; si < 4; ++si)
#pragma unroll
                for (int sj = 0; sj < 4; ++sj)
                    acc[si][sj] = MFMA16(a[si], b[sj], acc[si][sj]);
        }
        __syncthreads();
    }
}

// Epilogue: repack the 128x128 bf16 C-tile through cbuf (=Ast, free after
// the K-loop) so global stores are b128.
__device__ __forceinline__ void epilogue_bf16(
    f32x4 acc[4][4], short* cbuf,
    short* __restrict__ out, size_t obase, int ostride)
{
    const int tid = threadIdx.x;
    const int l15 = tid & 15, quad = (tid >> 4) & 3, wv = tid >> 6;
    const int wi = (wv >> 1) * 64, wj = (wv & 1) * 64;
    __syncthreads();
#pragma unroll
    for (int si = 0; si < 4; ++si)
#pragma unroll
        for (int sj = 0; sj < 4; ++sj)
#pragma unroll
            for (int rr = 0; rr < 4; ++rr)
                cbuf[(wi + si * 16 + quad * 4 + rr) * 128 + wj + sj * 16 + l15] =
                    f2b(acc[si][sj][rr]);
    __syncthreads();
#pragma unroll
    for (int pass = 0; pass < 8; ++pass) {
        const int row = pass * 16 + (tid >> 4);     // 0..127
        bf16x8 vchunk = *(const bf16x8*)(cbuf + row * 128 + l15 * 8);
        *(bf16x8*)(out + obase + (size_t)row * ostride + l15 * 8) = vchunk;
    }
}

// ---------------------------------------------------------------------------
// prep: fused transpose+convert (id<1536), weight convert (id<2112),
// amap zero (id>=2112). grid 2120.
// ---------------------------------------------------------------------------
__global__ __launch_bounds__(256) void prep(
    const float* __restrict__ Xq, const float* __restrict__ Xc,
    const float* __restrict__ w0, const float* __restrict__ w1,
    const float* __restrict__ w2, const float* __restrict__ w3,
    short* __restrict__ Xtq, short* __restrict__ Xtc,
    short* __restrict__ o0, short* __restrict__ o1,
    short* __restrict__ o2, short* __restrict__ o3,
    float* __restrict__ amap)
{
    __shared__ float tile[64][65];
    const int id = blockIdx.x, tid = threadIdx.x;
    if (id < 1536) {
        const int zz = id % 16, t = id / 16;
        const int n0 = (t % 16) * 64, c0 = (t / 16) * 64;
        const float* X = (zz < 8) ? Xq : Xc;
        short* Xt      = (zz < 8) ? Xtq : Xtc;
        const int b = zz & 7;
        const int tx = tid & 15, ty = tid >> 4;
#pragma unroll
        for (int rr = 0; rr < 4; ++rr) {
            const int c = rr * 16 + ty;
            float4 v = *(const float4*)&X[((size_t)(b * CCH + c0 + c)) * NTOK + n0 + tx * 4];
            tile[c][tx * 4 + 0] = v.x; tile[c][tx * 4 + 1] = v.y;
            tile[c][tx * 4 + 2] = v.z; tile[c][tx * 4 + 3] = v.w;
        }
        __syncthreads();
        const int n = tid >> 2, cb = (tid & 3) * 16;
        short tmp[16];
#pragma unroll
        for (int cc = 0; cc < 16; ++cc) tmp[cc] = f2b(tile[cb + cc][n]);
        short* dst = &Xt[((size_t)(b * NTOK + n0 + n)) * CCH + c0 + cb];
        *(int4*)dst = *(int4*)&tmp[0];
        *(int4*)(dst + 8) = *(int4*)&tmp[8];
    } else if (id < 2112) {
        const int w = id - 1536;
        const int which = w / 144;
        const int idx = (w % 144) * 256 + tid;
        const float* s = which == 0 ? w0 : which == 1 ? w1 : which == 2 ? w2 : w3;
        short* d       = which == 0 ? o0 : which == 1 ? o1 : which == 2 ? o2 : o3;
        float4 v = ((const float4*)s)[idx];
        short4 o = make_short4(f2b(v.x), f2b(v.y), f2b(v.z), f2b(v.w));
        ((short4*)d)[idx] = o;
    } else {
        const int o = (id - 2112) * 1024 + tid * 4;
        float4 z = {0.f, 0.f, 0.f, 0.f};
        *(float4*)&amap[o] = z;
    }
}

// ---------------------------------------------------------------------------
// Fused QKV projection, 128x128 tiles. 576 blocks: b=id%8 (XCD-local),
// r=id/8: which=r/24 (0:Q,1:K tok-major; 2:V ch-major), tt=r%24.
// Q output pre-scaled by QSCALE.
// ---------------------------------------------------------------------------
__global__ __launch_bounds__(256, 2) void gemm_qkv(
    const short* __restrict__ xtq, const short* __restrict__ xtc,
    const short* __restrict__ wq, const short* __restrict__ wk,
    const short* __restrict__ wvm,
    short* __restrict__ qout, short* __restrict__ kout, short* __restrict__ vout)
{
    __shared__ __align__(16) short Ast[2][8192];
    __shared__ __align__(16) short Bst[2][8192];
    const int id = blockIdx.x;
    const int b = id & 7, r = id >> 3;
    const int which = r / 24, tt = r % 24;

    const short *Ag, *Bg;
    short* out;
    size_t obase;
    int ostride;
    if (which < 2) {
        const int it = tt / 3, jt = tt % 3;
        const short* x = (which == 0) ? xtq : xtc;
        const short* W = (which == 0) ? wq : wk;
        Ag = x + ((size_t)(b * NTOK + it * 128)) * CCH;
        Bg = W + (size_t)(jt * 128) * CCH;
        out = (which == 0) ? qout : kout;
        obase = ((size_t)(b * NTOK + it * 128)) * CCH + jt * 128;
        ostride = CCH;
    } else {
        const int ct = tt % 3, nt = tt / 3;
        Ag = wvm + (size_t)(ct * 128) * CCH;
        Bg = xtc + ((size_t)(b * NTOK + nt * 128)) * CCH;
        out = vout;
        obase = ((size_t)(b * CCH + ct * 128)) * NTOK + nt * 128;
        ostride = NTOK;
    }

    f32x4 z4 = {0.f, 0.f, 0.f, 0.f};
    f32x4 acc[4][4];
#pragma unroll
    for (int si = 0; si < 4; ++si)
#pragma unroll
        for (int sj = 0; sj < 4; ++sj) acc[si][sj] = z4;

    gemm128_core(Ag, Bg, &Ast[0][0], &Bst[0][0], acc);

    if (which == 0) {
#pragma unroll
        for (int si = 0; si < 4; ++si)
#pragma unroll
            for (int sj = 0; sj < 4; ++sj)
#pragma unroll
                for (int rr = 0; rr < 4; ++rr)
                    acc[si][sj][rr] *= QSCALE;
    }
    epilogue_bf16(acc, &Ast[0][0], out, obase, ostride);
}

// ---------------------------------------------------------------------------
// Output projection, 128x128 tiles, fp32 out + bias. 192 blocks.
// ---------------------------------------------------------------------------
__global__ __launch_bounds__(256, 2) void o_proj(
    const short* __restrict__ wo, const short* __restrict__ omid,
    const float* __restrict__ bias, float* __restrict__ Y)
{
    __shared__ __align__(16) short Ast[2][8192];
    __shared__ __align__(16) short Bst[2][8192];
    const int id = blockIdx.x;
    const int b = id & 7, r = id >> 3;
    const int ct = r % 3, nt = r / 3;

    const short* Ag = wo + (size_t)(ct * 128) * CCH;
    const short* Bg = omid + ((size_t)(b * NTOK + nt * 128)) * CCH;

    f32x4 z4 = {0.f, 0.f, 0.f, 0.f};
    f32x4 acc[4][4];
#pragma unroll
    for (int si = 0; si < 4; ++si)
#pragma unroll
        for (int sj = 0; sj < 4; ++sj) acc[si][sj] = z4;

    gemm128_core(Ag, Bg, &Ast[0][0], &Bst[0][0], acc);

    const int tid = threadIdx.x;
    const int l15 = tid & 15, quad = (tid >> 4) & 3, wv = tid >> 6;
    const int wi = (wv >> 1) * 64, wj = (wv & 1) * 64;
#pragma unroll
    for (int si = 0; si < 4; ++si) {
#pragma unroll
        for (int rr = 0; rr < 4; ++rr) {
            const int ch = ct * 128 + wi + si * 16 + quad * 4 + rr;
            const float bv = bias[ch];
#pragma unroll
            for (int sj = 0; sj < 4; ++sj)
                Y[((size_t)(b * CCH + ch)) * NTOK + nt * 128 + wj + sj * 16 + l15] =
                    acc[si][sj][rr] + bv;
        }
    }
}

// ---------------------------------------------------------------------------
// Fused attention — r4-proven TWO-PASS structure (no per-thread e storage,
// no spill). Q pre-scaled by QSCALE so exp is bare v_exp (exp2f).
// Pass 1: den_i = sum_j exp2(S_ij)
// Pass 2: restage K+V; P normalized at Pst write (xor-swizzled chunks);
//         PV MFMA; colsum via shfl + colbuf double-buffer.
// ---------------------------------------------------------------------------
__global__ __launch_bounds__(256) void attn(
    const short* __restrict__ qt, const short* __restrict__ kt,
    const short* __restrict__ vc, short* __restrict__ omid,
    float* __restrict__ amap)
{
    __shared__ __align__(16) short Kst[2][64 * 64];   // 16 KB
    __shared__ __align__(16) short Vst[2][64 * 64];   // 16 KB
    __shared__ __align__(16) short Pst[4][16][64];    // 8 KB, chunk-xor swizzled
    __shared__ float colbuf[2][4][64];                // 2 KB

    const int tid = threadIdx.x, lane = tid & 63;
    const int l15 = tid & 15, quad = (tid >> 4) & 3, wv = tid >> 6;
    const int id = blockIdx.x;
    const int b = id & 7, rr_ = id >> 3;
    const int h = rr_ % 6, i0 = (rr_ / 6) * 64;

    const size_t hoff = (size_t)b * NTOK * CCH + h * DHEAD;
    const short* Kg = kt + hoff;                                   // stride CCH
    const short* Vg = vc + ((size_t)(b * CCH + h * DHEAD)) * NTOK; // stride NTOK

    const short* qp = qt + hoff + (size_t)(i0 + wv * 16 + l15) * CCH + quad * 8;
    const bf16x8 qa0 = *(const bf16x8*)qp;
    const bf16x8 qa1 = *(const bf16x8*)(qp + 32);

    // ---------------- Pass 1: denominators ----------------
    stage_tile(Kg, CCH, Kst[0], wv, lane);
    __syncthreads();

    float den[4] = {0.f, 0.f, 0.f, 0.f};
    for (int jt = 0; jt < 16; ++jt) {
        const int cur = jt & 1;
        if (jt < 15)
            stage_tile(Kg + (size_t)(jt + 1) * 64 * CCH, CCH, Kst[cur ^ 1], wv, lane);
        f32x4 z4 = {0.f, 0.f, 0.f, 0.f};
        f32x4 s[4] = {z4, z4, z4, z4};
#pragma unroll
        for (int ns = 0; ns < 4; ++ns) {
            const int row = ns * 16 + l15;
            bf16x8 k0 = frag_read(Kst[cur], row, quad);
            bf16x8 k1 = frag_read(Kst[cur], row, quad + 4);
            s[ns] = MFMA16(qa0, k0, s[ns]);
            s[ns] = MFMA16(qa1, k1, s[ns]);
        }
#pragma unroll
        for (int ns = 0; ns < 4; ++ns)
#pragma unroll
            for (int r = 0; r < 4; ++r)
                den[r] += exp2f(s[ns][r]);
        __syncthreads();
    }
#pragma unroll
    for (int r = 0; r < 4; ++r) {
        den[r] += __shfl_xor(den[r], 1);
        den[r] += __shfl_xor(den[r], 2);
        den[r] += __shfl_xor(den[r], 4);
        den[r] += __shfl_xor(den[r], 8);
    }
    float rden[4];
#pragma unroll
    for (int r = 0; r < 4; ++r) rden[r] = 1.0f / den[r];

    // ---------------- Pass 2: P, PV, colsums ----------------
    stage_tile(Kg, CCH, Kst[0], wv, lane);
    stage_tile(Vg, NTOK, Vst[0], wv, lane);
    __syncthreads();

    f32x4 z4o = {0.f, 0.f, 0.f, 0.f};
    f32x4 oacc[4] = {z4o, z4o, z4o, z4o};
    for (int jt = 0; jt < 16; ++jt) {
        const int cur = jt & 1;
        if (jt < 15) {
            stage_tile(Kg + (size_t)(jt + 1) * 64 * CCH, CCH, Kst[cur ^ 1], wv, lane);
            stage_tile(Vg + (size_t)(jt + 1) * 64, NTOK, Vst[cur ^ 1], wv, lane);
        }
        f32x4 s[4] = {z4o, z4o, z4o, z4o};
#pragma unroll
        for (int ns = 0; ns < 4; ++ns) {
            const int row = ns * 16 + l15;
            bf16x8 k0 = frag_read(Kst[cur], row, quad);
            bf16x8 k1 = frag_read(Kst[cur], row, quad + 4);
            s[ns] = MFMA16(qa0, k0, s[ns]);
            s[ns] = MFMA16(qa1, k1, s[ns]);
        }
        float p[4][4];
#pragma unroll
        for (int ns = 0; ns < 4; ++ns)
#pragma unroll
            for (int r = 0; r < 4; ++r)
                p[ns][r] = exp2f(s[ns][r]) * rden[r];

        // column sums over this wave's 16 i-rows
#pragma unroll
        for (int ns = 0; ns < 4; ++ns) {
            float cs = p[ns][0] + p[ns][1] + p[ns][2] + p[ns][3];
            cs += __shfl_xor(cs, 16);
            cs += __shfl_xor(cs, 32);
            if (quad == 0) colbuf[cur][wv][ns * 16 + l15] = cs;
        }

        // P -> per-wave swizzled LDS strip (A-operand layout for PV)
#pragma unroll
        for (int ns = 0; ns < 4; ++ns) {
            const int c = ns * 2 + (l15 >> 3);
#pragma unroll
            for (int r = 0; r < 4; ++r) {
                const int row = quad * 4 + r;
                Pst[wv][row][((c ^ (row & 7)) << 3) | (l15 & 7)] = f2b(p[ns][r]);
            }
        }
        asm volatile("" ::: "memory");
        const int pc0 = quad ^ (l15 & 7);
        const int pc1 = (quad + 4) ^ (l15 & 7);
        bf16x8 pa0 = *(const bf16x8*)&Pst[wv][l15][pc0 * 8];
        bf16x8 pa1 = *(const bf16x8*)&Pst[wv][l15][pc1 * 8];
        asm volatile("" ::: "memory");

#pragma unroll
        for (int ds = 0; ds < 4; ++ds) {
            const int row = ds * 16 + l15;
            bf16x8 v0 = frag_read(Vst[cur], row, quad);
            bf16x8 v1 = frag_read(Vst[cur], row, quad + 4);
            oacc[ds] = MFMA16(pa0, v0, oacc[ds]);
            oacc[ds] = MFMA16(pa1, v1, oacc[ds]);
        }
        __syncthreads();
        if (tid < 64) {
            const float t = colbuf[cur][0][tid] + colbuf[cur][1][tid]
                          + colbuf[cur][2][tid] + colbuf[cur][3][tid];
            atomicAdd(amap + (size_t)b * NTOK + jt * 64 + tid,
                      t * (1.0f / (HEADS * NTOK)));
        }
    }

    // store O (already normalized), token-major bf16
#pragma unroll
    for (int ds = 0; ds < 4; ++ds)
#pragma unroll
        for (int r = 0; r < 4; ++r) {
            const int i = i0 + wv * 16 + quad * 4 + r;
            omid[((size_t)(b * NTOK + i)) * CCH + h * DHEAD + ds * 16 + l15] =
                f2b(oacc[ds][r]);
        }
}

// ---------------------------------------------------------------------------
extern "C" void kernel_launch(void* const* d_in, const int* in_sizes, int n_in,
                              void* d_out, int out_size, void* d_ws, size_t ws_size,
                              hipStream_t stream)
{
    const float* query   = (const float*)d_in[0];
    const float* context = (const float*)d_in[1];
    const float* Wq      = (const float*)d_in[2];
    const float* Wk      = (const float*)d_in[3];
    const float* Wv      = (const float*)d_in[4];
    const float* Wo      = (const float*)d_in[5];
    const float* bo      = (const float*)d_in[6];

    float* out = (float*)d_out;                          // [8,384,1024] fp32
    const size_t out_elems = (size_t)BATCH * CCH * NTOK;
    float* attn_map = out + out_elems;                   // [8,1024] fp32

    short* ws = (short*)d_ws;
    const size_t XT = (size_t)BATCH * NTOK * CCH;
    const size_t WSZ = (size_t)CCH * CCH;
    short* xtq  = ws;
    short* xtc  = xtq + XT;
    short* wqb  = xtc + XT;
    short* wkb  = wqb + WSZ;
    short* wvb  = wkb + WSZ;
    short* wob  = wvb + WSZ;
    short* qtb  = wob + WSZ;
    short* ktb  = qtb + XT;
    short* vcb  = ktb + XT;
    short* omid = vcb + XT;

    const dim3 blk(256);

    prep<<<dim3(2120), blk, 0, stream>>>(query, context, Wq, Wk, Wv, Wo,
                                         xtq, xtc, wqb, wkb, wvb, wob, attn_map);

    gemm_qkv<<<dim3(576), blk, 0, stream>>>(xtq, xtc, wqb, wkb, wvb,
                                            qtb, ktb, vcb);

    attn<<<dim3(768), blk, 0, stream>>>(qtb, ktb, vcb, omid, attn_map);

    o_proj<<<dim3(192), blk, 0, stream>>>(wob, omid, bo, out);
}